// Round 1
// baseline (211.092 us; speedup 1.0000x reference)
//
#include <hip/hip_runtime.h>
#include <hip/hip_bf16.h>
#include <math.h>

// Problem constants
// B=2, T=4096, NF=256, H=4, C=63, DK=64, M=B*T=8192
#define GT_TILE 64
#define GT_BK 16

// C = A @ W^T  (+ optional relu). A: MxK row-major, W: NxK row-major, C: MxN.
// M multiple of 64, K multiple of 16. N guarded (for N=252 case).
template<bool RELU>
__global__ __launch_bounds__(256) void gemm_bt(const float* __restrict__ A,
                                               const float* __restrict__ W,
                                               float* __restrict__ Cout,
                                               int M, int N, int K) {
    // +4 pad: keeps 16B alignment for b128 reads, spreads transpose-store banks
    __shared__ float As[GT_BK][GT_TILE + 4];
    __shared__ float Bs[GT_BK][GT_TILE + 4];
    const int tid = threadIdx.x;
    const int tx = tid & 15;        // n-group
    const int ty = tid >> 4;        // m-group
    const int m0 = blockIdx.x * GT_TILE;
    const int n0 = blockIdx.y * GT_TILE;

    float acc[4][4] = {};

    for (int k0 = 0; k0 < K; k0 += GT_BK) {
        // Load 64x16 A tile (transposed into LDS: As[k][m])
        #pragma unroll
        for (int i = 0; i < 4; i++) {
            int idx = tid + i * 256;
            int m = idx >> 4;
            int k = idx & 15;
            As[k][m] = A[(size_t)(m0 + m) * K + k0 + k];
        }
        // Load 64x16 W tile (Bs[k][n] = W[n][k]), zero-pad n >= N
        #pragma unroll
        for (int i = 0; i < 4; i++) {
            int idx = tid + i * 256;
            int n = idx >> 4;
            int k = idx & 15;
            float w = 0.0f;
            if (n0 + n < N) w = W[(size_t)(n0 + n) * K + k0 + k];
            Bs[k][n] = w;
        }
        __syncthreads();
        #pragma unroll
        for (int kk = 0; kk < GT_BK; kk++) {
            float a[4], b[4];
            #pragma unroll
            for (int i = 0; i < 4; i++) a[i] = As[kk][ty * 4 + i];
            #pragma unroll
            for (int j = 0; j < 4; j++) b[j] = Bs[kk][tx * 4 + j];
            #pragma unroll
            for (int i = 0; i < 4; i++)
                #pragma unroll
                for (int j = 0; j < 4; j++)
                    acc[i][j] += a[i] * b[j];
        }
        __syncthreads();
    }

    #pragma unroll
    for (int i = 0; i < 4; i++) {
        int m = m0 + ty * 4 + i;
        #pragma unroll
        for (int j = 0; j < 4; j++) {
            int n = n0 + tx * 4 + j;
            if (n < N) {
                float val = acc[i][j];
                if (RELU) val = fmaxf(val, 0.0f);
                Cout[(size_t)m * N + n] = val;
            }
        }
    }
}

// Local dense-synthesizer attention: one wave per (b,h,t).
// weight: [B*T, 252] (col = h*63 + c), v: [B*T, 256] (col = h*64 + d)
// x out:  [B*T, 256] (col = h*64 + d)
__global__ __launch_bounds__(256) void attn_kernel(const float* __restrict__ weight,
                                                   const float* __restrict__ v,
                                                   float* __restrict__ x,
                                                   int B, int T) {
    const int C_ = 63, HALF = 31, H_ = 4;
    int wave = blockIdx.x * (blockDim.x >> 6) + (threadIdx.x >> 6);
    int lane = threadIdx.x & 63;
    int total = B * H_ * T;
    if (wave >= total) return;
    int t = wave % T;
    int h = (wave / T) % H_;
    int b = wave / (T * H_);

    // --- scores + softmax (lane = c for c < 63) ---
    int j = t + lane - HALF;
    bool valid = (lane < C_) && (j >= 0) && (j < T);
    float s = -INFINITY;
    if (valid) s = weight[(size_t)(b * T + t) * 252 + h * C_ + lane];

    float m = s;
    #pragma unroll
    for (int off = 32; off > 0; off >>= 1) m = fmaxf(m, __shfl_xor(m, off));
    float e = valid ? __expf(s - m) : 0.0f;
    float sum = e;
    #pragma unroll
    for (int off = 32; off > 0; off >>= 1) sum += __shfl_xor(sum, off);
    float p = e / sum;

    // --- PV: lane = d, serial over c with wave-uniform broadcast ---
    float acc = 0.0f;
    for (int c = 0; c < C_; c++) {
        float pc = __shfl(p, c);
        int jj = t + c - HALF;
        if (jj >= 0 && jj < T) {
            acc += pc * v[(size_t)(b * T + jj) * 256 + (h << 6) + lane];
        }
    }
    x[(size_t)(b * T + t) * 256 + (h << 6) + lane] = acc;
}

extern "C" void kernel_launch(void* const* d_in, const int* in_sizes, int n_in,
                              void* d_out, int out_size, void* d_ws, size_t ws_size,
                              hipStream_t stream) {
    const float* query = (const float*)d_in[0];
    // d_in[1] = key   (unused by reference)
    const float* value = (const float*)d_in[2];
    // d_in[3] = mask  (unused by reference)
    const float* w1    = (const float*)d_in[4];
    const float* w2    = (const float*)d_in[5];
    const float* w3    = (const float*)d_in[6];
    const float* w_out = (const float*)d_in[7];

    const int B = 2, T = 4096, M = B * T;   // M = 8192

    float* buf0 = (float*)d_ws;                       // q_relu, later x
    float* buf1 = buf0 + (size_t)M * 256;             // weight (M x 252)
    float* buf2 = buf1 + (size_t)M * 256;             // v

    dim3 blk(256);
    dim3 ggrid(M / GT_TILE, 4);   // N=256 or 252 -> 4 column tiles

    // 1) q_relu = relu(query @ w1^T)
    gemm_bt<true><<<ggrid, blk, 0, stream>>>(query, w1, buf0, M, 256, 256);
    // 2) weight = q_relu @ w2^T   (N = 252)
    gemm_bt<false><<<ggrid, blk, 0, stream>>>(buf0, w2, buf1, M, 252, 256);
    // 3) v = value @ w3^T
    gemm_bt<false><<<ggrid, blk, 0, stream>>>(value, w3, buf2, M, 256, 256);
    // 4) attention -> x (overwrites buf0; q_relu dead after step 2)
    int waves = B * 4 * T;                 // 32768
    attn_kernel<<<dim3(waves / 4), blk, 0, stream>>>(buf1, buf2, buf0, B, T);
    // 5) out = x @ w_out^T
    gemm_bt<false><<<ggrid, blk, 0, stream>>>(buf0, w_out, (float*)d_out, M, 256, 256);
}

// Round 2
// 66.811 us; speedup vs baseline: 3.1596x; 3.1596x over previous
//
#include <hip/hip_runtime.h>
#include <hip/hip_bf16.h>
#include <math.h>

typedef _Float16 f16x8 __attribute__((ext_vector_type(8)));
typedef _Float16 f16x4 __attribute__((ext_vector_type(4)));
typedef _Float16 f16x2 __attribute__((ext_vector_type(2)));
typedef float    f32x4 __attribute__((ext_vector_type(4)));

#define BM 64
#define BN 64
#define BK 64

// C = A @ W^T. A: MxK (fp32 or fp16 per AFP32), W: NxK fp32. Out fp16 or fp32.
// LDS tiles XOR-swizzled at 16B-chunk granularity: chunk' = chunk ^ (row&7).
template<bool AFP32, bool RELU, bool OUTF16>
__global__ __launch_bounds__(256) void gemm16(const void* __restrict__ Aptr,
                                              const float* __restrict__ W,
                                              void* __restrict__ Out,
                                              int M, int N, int K) {
    __shared__ __align__(16) _Float16 As[BM * BK];
    __shared__ __align__(16) _Float16 Bs[BN * BK];
    const int tid  = threadIdx.x;
    const int lane = tid & 63;
    const int wid  = tid >> 6;
    const int wm   = wid >> 1, wn = wid & 1;     // 2x2 wave grid, 32x32 per wave
    const int m0 = blockIdx.x * BM;
    const int n0 = blockIdx.y * BN;

    f32x4 acc[2][2] = {};

    for (int kt = 0; kt < K; kt += BK) {
        // ---- stage A tile (64 rows x 64 k) ----
        if (AFP32) {
            const float* A = (const float*)Aptr;
            #pragma unroll
            for (int it = 0; it < 4; ++it) {
                int r  = it * 16 + (tid >> 4);
                int c4 = tid & 15;                       // 4-float chunk
                float4 av = *(const float4*)&A[(size_t)(m0 + r) * K + kt + c4 * 4];
                f16x4 hv = { (_Float16)av.x, (_Float16)av.y, (_Float16)av.z, (_Float16)av.w };
                int addr = r * BK + ((((c4 >> 1) ^ (r & 7)) << 3) + ((c4 & 1) << 2));
                *(f16x4*)&As[addr] = hv;
            }
        } else {
            const _Float16* A = (const _Float16*)Aptr;
            #pragma unroll
            for (int it = 0; it < 2; ++it) {
                int r = it * 32 + (tid >> 3);
                int c = tid & 7;                         // 8-elem (16B) chunk
                f16x8 v = *(const f16x8*)&A[(size_t)(m0 + r) * K + kt + c * 8];
                *(f16x8*)&As[r * BK + ((c ^ (r & 7)) << 3)] = v;
            }
        }
        // ---- stage B tile from fp32 W [N][K], zero rows >= N ----
        #pragma unroll
        for (int it = 0; it < 4; ++it) {
            int r  = it * 16 + (tid >> 4);
            int c4 = tid & 15;
            float4 wv = make_float4(0.f, 0.f, 0.f, 0.f);
            if (n0 + r < N) wv = *(const float4*)&W[(size_t)(n0 + r) * K + kt + c4 * 4];
            f16x4 hv = { (_Float16)wv.x, (_Float16)wv.y, (_Float16)wv.z, (_Float16)wv.w };
            int addr = r * BK + ((((c4 >> 1) ^ (r & 7)) << 3) + ((c4 & 1) << 2));
            *(f16x4*)&Bs[addr] = hv;
        }
        __syncthreads();

        #pragma unroll
        for (int ks = 0; ks < 2; ++ks) {
            f16x8 af[2], bf[2];
            #pragma unroll
            for (int i = 0; i < 2; ++i) {
                int row = wm * 32 + i * 16 + (lane & 15);
                int ch  = ks * 4 + (lane >> 4);
                af[i] = *(const f16x8*)&As[row * BK + ((ch ^ (row & 7)) << 3)];
            }
            #pragma unroll
            for (int j = 0; j < 2; ++j) {
                int row = wn * 32 + j * 16 + (lane & 15);
                int ch  = ks * 4 + (lane >> 4);
                bf[j] = *(const f16x8*)&Bs[row * BK + ((ch ^ (row & 7)) << 3)];
            }
            #pragma unroll
            for (int i = 0; i < 2; ++i)
                #pragma unroll
                for (int j = 0; j < 2; ++j)
                    acc[i][j] = __builtin_amdgcn_mfma_f32_16x16x32_f16(af[i], bf[j], acc[i][j], 0, 0, 0);
        }
        __syncthreads();
    }

    // C/D layout (m89-verified): col = lane&15, row = (lane>>4)*4 + reg
    #pragma unroll
    for (int i = 0; i < 2; ++i) {
        #pragma unroll
        for (int j = 0; j < 2; ++j) {
            #pragma unroll
            for (int r = 0; r < 4; ++r) {
                int m = m0 + wm * 32 + i * 16 + ((lane >> 4) << 2) + r;
                int n = n0 + wn * 32 + j * 16 + (lane & 15);
                if (n < N) {
                    float val = acc[i][j][r];
                    if (RELU) val = fmaxf(val, 0.f);
                    if (OUTF16) ((_Float16*)Out)[(size_t)m * N + n] = (_Float16)val;
                    else        ((float*)Out)[(size_t)m * N + n] = val;
                }
            }
        }
    }
}

// Local attention. Block = one (b, head, 64-t tile). 4 waves, wave = 16 t's,
// processed 2 at a time (lane half hf = lane>>5 owns t = tbase + 2i + hf).
__global__ __launch_bounds__(256) void attn16(const _Float16* __restrict__ weight16,
                                              const _Float16* __restrict__ v16,
                                              _Float16* __restrict__ x16) {
    const int T = 4096, CC = 63, HALFW = 31;
    __shared__ __align__(16) _Float16 vwin[126 * 64];
    __shared__ float pbuf[4][2][64];

    const int bid  = blockIdx.x;
    const int tt0  = (bid & 63) << 6;
    const int head = (bid >> 6) & 3;
    const int b    = bid >> 8;
    const int tid  = threadIdx.x;
    const int lane = tid & 63;
    const int wid  = tid >> 6;
    const size_t rowbase = (size_t)b * T;

    // stage v window: rows j = tt0-31+r, r in [0,126), 64 fp16 each
    #pragma unroll
    for (int it = 0; it < 4; ++it) {
        int idx = it * 256 + tid;
        int r   = idx >> 3;
        int c8  = idx & 7;
        if (r < 126) {
            int j = tt0 - HALFW + r;
            uint4 d = make_uint4(0u, 0u, 0u, 0u);
            if (j >= 0 && j < T)
                d = *(const uint4*)&v16[(rowbase + j) * 256 + head * 64 + c8 * 8];
            *(uint4*)&vwin[r * 64 + c8 * 8] = d;
        }
    }
    __syncthreads();

    const int hf = lane >> 5;       // which of the 2 concurrent t's
    const int c  = lane & 31;       // score column (and c+32)
    const int tbase = tt0 + wid * 16;

    for (int i = 0; i < 8; ++i) {
        int t  = tbase + 2 * i + hf;
        const _Float16* wrow = weight16 + (rowbase + t) * 252 + head * 63;
        int c1 = c + 32;
        int j0 = t + c  - HALFW;
        int j1 = t + c1 - HALFW;
        bool ok0 = (j0 >= 0) && (j0 < T);
        bool ok1 = (c1 < CC) && (j1 >= 0) && (j1 < T);
        float s0 = ok0 ? (float)wrow[c]  : -INFINITY;
        float s1 = ok1 ? (float)wrow[c1] : -INFINITY;

        float mx = fmaxf(s0, s1);
        #pragma unroll
        for (int off = 16; off > 0; off >>= 1) mx = fmaxf(mx, __shfl_xor(mx, off));
        float e0 = ok0 ? __expf(s0 - mx) : 0.f;
        float e1 = ok1 ? __expf(s1 - mx) : 0.f;
        float sum = e0 + e1;
        #pragma unroll
        for (int off = 16; off > 0; off >>= 1) sum += __shfl_xor(sum, off);
        float inv = 1.0f / sum;
        pbuf[wid][hf][c]  = e0 * inv;
        pbuf[wid][hf][c1] = e1 * inv;   // c1==63 is a zero pad slot

        float acc0 = 0.f, acc1 = 0.f;
        const int rbase = t - tt0;      // 0..63
        #pragma unroll
        for (int cc = 0; cc < CC; ++cc) {
            float pc = pbuf[wid][hf][cc];
            f16x2 v2 = *(const f16x2*)&vwin[(rbase + cc) * 64 + ((lane & 31) << 1)];
            acc0 += pc * (float)v2[0];
            acc1 += pc * (float)v2[1];
        }
        f16x2 o = { (_Float16)acc0, (_Float16)acc1 };
        *(f16x2*)&x16[(rowbase + t) * 256 + head * 64 + ((lane & 31) << 1)] = o;
    }
}

extern "C" void kernel_launch(void* const* d_in, const int* in_sizes, int n_in,
                              void* d_out, int out_size, void* d_ws, size_t ws_size,
                              hipStream_t stream) {
    const float* query = (const float*)d_in[0];
    const float* value = (const float*)d_in[2];
    const float* w1    = (const float*)d_in[4];
    const float* w2    = (const float*)d_in[5];
    const float* w3    = (const float*)d_in[6];
    const float* w_out = (const float*)d_in[7];
    const int M = 8192;

    char* ws = (char*)d_ws;
    _Float16* B1 = (_Float16*)ws;                          // q_relu16, then v16
    _Float16* B2 = (_Float16*)(ws + 4u * 1024 * 1024);     // weight16 [M][252]
    _Float16* B3 = (_Float16*)(ws + 8u * 1024 * 1024);     // x16 [M][256]

    dim3 blk(256);
    dim3 g1(M / BM, 4);

    // 1) q_relu16 = relu(query @ w1^T)            (A fp32, out fp16)
    gemm16<true,  true,  true ><<<g1, blk, 0, stream>>>(query, w1, B1, M, 256, 256);
    // 2) weight16 = q_relu16 @ w2^T  (N=252)      (A fp16, out fp16)
    gemm16<false, false, true ><<<g1, blk, 0, stream>>>(B1,    w2, B2, M, 252, 256);
    // 3) v16 = value @ w3^T  (overwrites B1; q_relu dead after step 2)
    gemm16<true,  false, true ><<<g1, blk, 0, stream>>>(value, w3, B1, M, 256, 256);
    // 4) attention -> x16
    attn16<<<dim3(512), blk, 0, stream>>>(B2, B1, B3);
    // 5) out = x16 @ w_out^T                      (A fp16, out fp32)
    gemm16<false, false, false><<<g1, blk, 0, stream>>>(B3, w_out, (float*)d_out, M, 256, 256);
}

// Round 3
// 47.539 us; speedup vs baseline: 4.4404x; 1.4054x over previous
//
#include <hip/hip_runtime.h>
#include <hip/hip_bf16.h>
#include <math.h>

typedef _Float16 f16x8 __attribute__((ext_vector_type(8)));
typedef _Float16 f16x2 __attribute__((ext_vector_type(2)));
typedef float    f32x4 __attribute__((ext_vector_type(4)));

// XOR-swizzle: 16B chunk index within a 256-elem (512B) row, rule: low3 ^= row&7
__device__ __host__ __forceinline__ int swz(int ch, int row) {
    return (ch & 24) | ((ch & 7) ^ (row & 7));
}

__device__ __forceinline__ void gld16(const void* g, void* l) {
    __builtin_amdgcn_global_load_lds((const __attribute__((address_space(1))) void*)g,
                                     (__attribute__((address_space(3))) void*)l, 16, 0, 0);
}

// ---- weight converter: fp32 [rows][256] -> fp16 swizzled; w2 zero-padded to 256 rows
__global__ __launch_bounds__(256) void convw(const float* __restrict__ w1,
                                             const float* __restrict__ w2,
                                             const float* __restrict__ w3,
                                             const float* __restrict__ wo,
                                             _Float16* __restrict__ o1,
                                             _Float16* __restrict__ o2,
                                             _Float16* __restrict__ o3,
                                             _Float16* __restrict__ oo) {
    int gid = blockIdx.x * 256 + threadIdx.x;        // 32768 total
    const float* src; _Float16* dst; int local;
    if (gid < 8192)       { src = w1; dst = o1; local = gid; }
    else if (gid < 16256) { src = w2; dst = o2; local = gid - 8192; }
    else if (gid < 16384) {                          // zero-fill w2 rows 252..255
        int l = gid - 16256;
        int row = 252 + (l >> 5), ch = l & 31;
        f16x8 z = {};
        *(f16x8*)&o2[row * 256 + ch * 8] = z;
        return;
    }
    else if (gid < 24576) { src = w3; dst = o3; local = gid - 16384; }
    else                  { src = wo; dst = oo; local = gid - 24576; }
    int row = local >> 5, ch = local & 31;
    float4 lo = *(const float4*)&src[row * 256 + ch * 8];
    float4 hi = *(const float4*)&src[row * 256 + ch * 8 + 4];
    f16x8 h = { (_Float16)lo.x, (_Float16)lo.y, (_Float16)lo.z, (_Float16)lo.w,
                (_Float16)hi.x, (_Float16)hi.y, (_Float16)hi.z, (_Float16)hi.w };
    *(f16x8*)&dst[row * 256 + swz(ch, row) * 8] = h;
}

// ---- full-K GEMM: C[64x64] = A[64x256] @ B^T, B = fp16 swizzled [256][256]
// AM: 0 = A fp32 natural (reg-staged cvt, swizzled ds_write)
//     1 = A fp16 pre-swizzled (global_load_lds direct)
// OM: 0 = fp16 swizzled, 1 = fp16 natural (stride/guard Nst), 2 = fp32 natural
template<int AM, bool RELU, int OM>
__global__ __launch_bounds__(256) void gemm_fullk(const void* __restrict__ Aptr,
                                                  const _Float16* __restrict__ Bsw,
                                                  void* __restrict__ Out,
                                                  int Nst) {
    __shared__ __align__(16) _Float16 As[64 * 256];
    __shared__ __align__(16) _Float16 Bs[64 * 256];
    const int tid  = threadIdx.x;
    const int lane = tid & 63;
    const int wid  = tid >> 6;
    const int wm   = wid >> 1, wn = wid & 1;
    const int m0   = blockIdx.x * 64;
    const int n0   = blockIdx.y * 64;

    // ---- stage B (rows n0..n0+63, contiguous 32KB, already swizzled in global)
    {
        const char* Bb = (const char*)Bsw + (size_t)n0 * 512;
        char* Bl = (char*)Bs;
        #pragma unroll
        for (int i = 0; i < 8; ++i) {
            int j = wid * 8 + i;
            gld16(Bb + j * 1024 + lane * 16, Bl + j * 1024);
        }
    }
    // ---- stage A
    if (AM == 1) {
        const char* Ab = (const char*)Aptr + (size_t)m0 * 512;
        char* Al = (char*)As;
        #pragma unroll
        for (int i = 0; i < 8; ++i) {
            int j = wid * 8 + i;
            gld16(Ab + j * 1024 + lane * 16, Al + j * 1024);
        }
    } else {
        const float* A = (const float*)Aptr;
        #pragma unroll
        for (int i = 0; i < 8; ++i) {
            int slot = i * 256 + tid;
            int row = slot >> 5, ch = slot & 31;
            const float* p = &A[(size_t)(m0 + row) * 256 + ch * 8];
            float4 lo = *(const float4*)p;
            float4 hi = *(const float4*)(p + 4);
            f16x8 h = { (_Float16)lo.x, (_Float16)lo.y, (_Float16)lo.z, (_Float16)lo.w,
                        (_Float16)hi.x, (_Float16)hi.y, (_Float16)hi.z, (_Float16)hi.w };
            *(f16x8*)&As[row * 256 + swz(ch, row) * 8] = h;
        }
    }
    __syncthreads();

    // ---- compute: 2x2 16x16 tiles per wave, K=256 in 8 MFMA steps
    f32x4 acc[2][2] = {};
    #pragma unroll
    for (int ks = 0; ks < 8; ++ks) {
        int ch = ks * 4 + (lane >> 4);
        f16x8 af[2], bf[2];
        #pragma unroll
        for (int i = 0; i < 2; ++i) {
            int row = wm * 32 + i * 16 + (lane & 15);
            af[i] = *(const f16x8*)&As[row * 256 + swz(ch, row) * 8];
        }
        #pragma unroll
        for (int j = 0; j < 2; ++j) {
            int row = wn * 32 + j * 16 + (lane & 15);
            bf[j] = *(const f16x8*)&Bs[row * 256 + swz(ch, row) * 8];
        }
        #pragma unroll
        for (int i = 0; i < 2; ++i)
            #pragma unroll
            for (int j = 0; j < 2; ++j)
                acc[i][j] = __builtin_amdgcn_mfma_f32_16x16x32_f16(af[i], bf[j], acc[i][j], 0, 0, 0);
    }

    // ---- store (C/D layout: col = lane&15, row = (lane>>4)*4 + r)
    #pragma unroll
    for (int i = 0; i < 2; ++i) {
        #pragma unroll
        for (int j = 0; j < 2; ++j) {
            #pragma unroll
            for (int r = 0; r < 4; ++r) {
                int m = m0 + wm * 32 + i * 16 + ((lane >> 4) << 2) + r;
                int n = n0 + wn * 32 + j * 16 + (lane & 15);
                float val = acc[i][j][r];
                if (RELU) val = fmaxf(val, 0.f);
                if (OM == 0) {
                    int np = swz(n >> 3, m) * 8 + (n & 7);
                    ((_Float16*)Out)[(size_t)m * 256 + np] = (_Float16)val;
                } else if (OM == 1) {
                    if (n < Nst) ((_Float16*)Out)[(size_t)m * Nst + n] = (_Float16)val;
                } else {
                    ((float*)Out)[(size_t)m * 256 + n] = val;
                }
            }
        }
    }
}

// ---- local attention: block = (b, head, 64-t tile); x written fp16 SWIZZLED
__global__ __launch_bounds__(256) void attn16(const _Float16* __restrict__ weight16,
                                              const _Float16* __restrict__ v16,
                                              _Float16* __restrict__ x16) {
    const int T = 4096, CC = 63, HALFW = 31;
    __shared__ __align__(16) _Float16 vwin[126 * 64];
    __shared__ float pbuf[4][2][64];

    const int bid  = blockIdx.x;
    const int tt0  = (bid & 63) << 6;
    const int head = (bid >> 6) & 3;
    const int b    = bid >> 8;
    const int tid  = threadIdx.x;
    const int lane = tid & 63;
    const int wid  = tid >> 6;
    const size_t rowbase = (size_t)b * T;

    #pragma unroll
    for (int it = 0; it < 4; ++it) {
        int idx = it * 256 + tid;
        int r   = idx >> 3;
        int c8  = idx & 7;
        if (r < 126) {
            int j = tt0 - HALFW + r;
            uint4 d = make_uint4(0u, 0u, 0u, 0u);
            if (j >= 0 && j < T)
                d = *(const uint4*)&v16[(rowbase + j) * 256 + head * 64 + c8 * 8];
            *(uint4*)&vwin[r * 64 + c8 * 8] = d;
        }
    }
    __syncthreads();

    const int hf = lane >> 5;
    const int c  = lane & 31;
    const int tbase = tt0 + wid * 16;

    for (int i = 0; i < 8; ++i) {
        int t  = tbase + 2 * i + hf;
        const _Float16* wrow = weight16 + (rowbase + t) * 252 + head * 63;
        int c1 = c + 32;
        int j0 = t + c  - HALFW;
        int j1 = t + c1 - HALFW;
        bool ok0 = (j0 >= 0) && (j0 < T);
        bool ok1 = (c1 < CC) && (j1 >= 0) && (j1 < T);
        float s0 = ok0 ? (float)wrow[c]  : -INFINITY;
        float s1 = ok1 ? (float)wrow[c1] : -INFINITY;

        float mx = fmaxf(s0, s1);
        #pragma unroll
        for (int off = 16; off > 0; off >>= 1) mx = fmaxf(mx, __shfl_xor(mx, off));
        float e0 = ok0 ? __expf(s0 - mx) : 0.f;
        float e1 = ok1 ? __expf(s1 - mx) : 0.f;
        float sum = e0 + e1;
        #pragma unroll
        for (int off = 16; off > 0; off >>= 1) sum += __shfl_xor(sum, off);
        float inv = 1.0f / sum;
        pbuf[wid][hf][c]  = e0 * inv;
        pbuf[wid][hf][c1] = e1 * inv;

        float acc0 = 0.f, acc1 = 0.f;
        const int rbase = t - tt0;
        #pragma unroll
        for (int cc = 0; cc < CC; ++cc) {
            float pc = pbuf[wid][hf][cc];
            f16x2 v2 = *(const f16x2*)&vwin[(rbase + cc) * 64 + ((lane & 31) << 1)];
            acc0 += pc * (float)v2[0];
            acc1 += pc * (float)v2[1];
        }
        f16x2 o = { (_Float16)acc0, (_Float16)acc1 };
        int c2 = head * 64 + ((lane & 31) << 1);
        int c2s = swz(c2 >> 3, t) * 8 + (c2 & 7);
        *(f16x2*)&x16[(rowbase + t) * 256 + c2s] = o;
    }
}

extern "C" void kernel_launch(void* const* d_in, const int* in_sizes, int n_in,
                              void* d_out, int out_size, void* d_ws, size_t ws_size,
                              hipStream_t stream) {
    const float* query = (const float*)d_in[0];
    const float* value = (const float*)d_in[2];
    const float* w1    = (const float*)d_in[4];
    const float* w2    = (const float*)d_in[5];
    const float* w3    = (const float*)d_in[6];
    const float* w_out = (const float*)d_in[7];
    const int M = 8192;

    char* ws = (char*)d_ws;
    _Float16* qrelu  = (_Float16*)(ws);                       // 4 MB, swizzled
    _Float16* wgt16  = (_Float16*)(ws + (4u << 20));          // [M][252] natural
    _Float16* v16    = (_Float16*)(ws + (8u << 20));          // [M][256] natural
    _Float16* x16    = (_Float16*)(ws + (12u << 20));         // 4 MB, swizzled
    _Float16* w1_16  = (_Float16*)(ws + (16u << 20));         // 128 KB each, swizzled
    _Float16* w2_16  = w1_16 + 65536;
    _Float16* w3_16  = w2_16 + 65536;
    _Float16* wo_16  = w3_16 + 65536;

    dim3 blk(256);
    dim3 gg(M / 64, 4);

    convw<<<dim3(128), blk, 0, stream>>>(w1, w2, w3, w_out, w1_16, w2_16, w3_16, wo_16);
    // 1) q_relu16(swz) = relu(query @ w1^T)
    gemm_fullk<0, true,  0><<<gg, blk, 0, stream>>>(query, w1_16, qrelu, 256);
    // 2) weight16(nat,252) = q_relu16 @ w2^T
    gemm_fullk<1, false, 1><<<gg, blk, 0, stream>>>(qrelu, w2_16, wgt16, 252);
    // 3) v16(nat) = value @ w3^T
    gemm_fullk<0, false, 1><<<gg, blk, 0, stream>>>(value, w3_16, v16, 256);
    // 4) attention -> x16(swz)
    attn16<<<dim3(512), blk, 0, stream>>>(wgt16, v16, x16);
    // 5) out(fp32) = x16 @ w_out^T
    gemm_fullk<1, false, 2><<<gg, blk, 0, stream>>>(x16, wo_16, (float*)d_out, 256);
}